// Round 2
// baseline (88.865 us; speedup 1.0000x reference)
//
#include <hip/hip_runtime.h>

#define B_ 256
#define C_ 1000
#define D_ 512

typedef __bf16 bf16x8 __attribute__((ext_vector_type(8)));
typedef float  f32x4  __attribute__((ext_vector_type(4)));

__device__ __forceinline__ bf16x8 cvt8(float4 a, float4 b) {
    bf16x8 r;
    r[0] = (__bf16)a.x; r[1] = (__bf16)a.y; r[2] = (__bf16)a.z; r[3] = (__bf16)a.w;
    r[4] = (__bf16)b.x; r[5] = (__bf16)b.y; r[6] = (__bf16)b.z; r[7] = (__bf16)b.w;
    return r;
}

// Fully fused: logits GEMM (bf16 MFMA), x row norms, W Gram (MFMA A·A^T),
// normalization + quadratic-form epilogue. out[b,c] = ||l||^2 / ||l^T G_c l||^(1/2)
// with l_s = (x_b . W_cs) * invx_b * invn_cs  (== xn . Wn_cs).
//
// Block = 4 waves. blk -> ct (16 W-rows = 4 c's), bg; wave wv -> 16 b's.
// MFMA 16x16x32 bf16 D-layout: col(n)=lane&15 -> b, row(m)=quad*4+reg -> (c_local=quad, s=reg).
// A/B operand layout (identical): idx=lane&15, k=quad*8+j.
__global__ __launch_bounds__(256) void k_fused(const float* __restrict__ x,
                                               const float* __restrict__ W,
                                               float* __restrict__ out) {
    int blk = blockIdx.x;
    int ct = blk >> 2;          // 0..249, covers c = 4*ct .. 4*ct+3
    int bg = blk & 3;
    int t = threadIdx.x;
    int lane = t & 63, wv = t >> 6;
    int l15 = lane & 15, quad = lane >> 4;
    int b = (bg * 4 + wv) * 16 + l15;

    const float* wrow = W + (ct * 16 + l15) * D_ + quad * 8;
    const float* xrow = x + b * D_ + quad * 8;

    f32x4 acc_l = {0.f, 0.f, 0.f, 0.f};   // raw logits  L[4c+quad*?][b] per layout
    f32x4 acc_g = {0.f, 0.f, 0.f, 0.f};   // Gram[quad*4+reg][l15]
    float sn = 0.f;                        // partial ||x_b||^2 (this lane's quarter)

    #pragma unroll
    for (int ks = 0; ks < 16; ks++) {
        float4 wa = *(const float4*)(wrow + ks * 32);
        float4 wb = *(const float4*)(wrow + ks * 32 + 4);
        float4 xa = *(const float4*)(xrow + ks * 32);
        float4 xb = *(const float4*)(xrow + ks * 32 + 4);
        bf16x8 af = cvt8(wa, wb);
        bf16x8 bf = cvt8(xa, xb);
        sn += xa.x*xa.x + xa.y*xa.y + xa.z*xa.z + xa.w*xa.w
            + xb.x*xb.x + xb.y*xb.y + xb.z*xb.z + xb.w*xb.w;
        acc_l = __builtin_amdgcn_mfma_f32_16x16x32_bf16(af, bf, acc_l, 0, 0, 0);
        acc_g = __builtin_amdgcn_mfma_f32_16x16x32_bf16(af, af, acc_g, 0, 0, 0);
    }

    // full ||x_b||^2: combine the 4 quad-partners holding the same b (lanes l15+16k)
    sn += __shfl_xor(sn, 16);
    sn += __shfl_xor(sn, 32);
    float invx = 1.0f / fmaxf(sqrtf(sn), 1e-12f);

    // gather this lane's 4x4 Gram block: Gram[4*quad+s][4*quad+q] lives in
    // lane (quad*16 + 4*quad + q) = 20*quad + q, register s.
    float g[4][4];
    #pragma unroll
    for (int s = 0; s < 4; s++) {
        float v = acc_g[s];
        #pragma unroll
        for (int q = 0; q < 4; q++) g[s][q] = __shfl(v, 20 * quad + q);
    }

    float iv[4], l[4];
    #pragma unroll
    for (int s = 0; s < 4; s++) iv[s] = 1.0f / fmaxf(sqrtf(fmaxf(g[s][s], 0.f)), 1e-12f);
    #pragma unroll
    for (int s = 0; s < 4; s++) l[s] = acc_l[s] * invx * iv[s];

    float num = l[0]*l[0] + l[1]*l[1] + l[2]*l[2] + l[3]*l[3];
    float den2 = 0.f;
    #pragma unroll
    for (int s = 0; s < 4; s++) {
        float r = 0.f;
        #pragma unroll
        for (int q = 0; q < 4; q++) r += g[s][q] * iv[q] * l[q];
        den2 += l[s] * iv[s] * r;
    }
    float den = fmaxf(sqrtf(fmaxf(den2, 0.f)), 1e-12f);

    int c = ct * 4 + quad;
    out[b * C_ + c] = num / den;
}

extern "C" void kernel_launch(void* const* d_in, const int* in_sizes, int n_in,
                              void* d_out, int out_size, void* d_ws, size_t ws_size,
                              hipStream_t stream) {
    const float* x = (const float*)d_in[0];   // [256,512] fp32
    const float* W = (const float*)d_in[1];   // [1000,4,512] fp32
    float* out = (float*)d_out;               // [256,1000] fp32
    k_fused<<<1000, 256, 0, stream>>>(x, W, out);
}

// Round 3
// 69.803 us; speedup vs baseline: 1.2731x; 1.2731x over previous
//
#include <hip/hip_runtime.h>

#define B_ 256
#define C_ 1000
#define D_ 512

typedef __bf16 bf16x8 __attribute__((ext_vector_type(8)));
typedef float  f32x4  __attribute__((ext_vector_type(4)));

__device__ __forceinline__ bf16x8 cvt8(float4 a, float4 b) {
    bf16x8 r;
    r[0] = (__bf16)a.x; r[1] = (__bf16)a.y; r[2] = (__bf16)a.z; r[3] = (__bf16)a.w;
    r[4] = (__bf16)b.x; r[5] = (__bf16)b.y; r[6] = (__bf16)b.z; r[7] = (__bf16)b.w;
    return r;
}

// Pass 1: coalesced fp32 reads; convert to bf16; scatter 16B fragments into
// MFMA-operand-linear layout  [tile16][ks][quad][l15][8elems]  so the main
// kernel's wave loads are lane-contiguous (1 KB/instruction).
// Blocks 0..999: W (4000 rows). Blocks 1000..1063: x (256 rows) + invx.
__global__ __launch_bounds__(256) void k_pack(const float* __restrict__ x,
                                              const float* __restrict__ W,
                                              __bf16* __restrict__ Wf,
                                              __bf16* __restrict__ xf,
                                              float* __restrict__ invx) {
    int blk = blockIdx.x;
    int t = threadIdx.x;
    if (blk < 1000) {
        int n = blk * 256 + t;          // 8-elem chunk id, 256000 total
        int r = n >> 6;                 // W row 0..3999 (one wave == one row)
        int j = n & 63;                 // chunk within row
        const float* src = W + r * D_ + j * 8;
        float4 a = *(const float4*)src;
        float4 b = *(const float4*)(src + 4);
        int ct = r >> 4, l15 = r & 15, ks = j >> 2, quad = j & 3;
        int idx = ((ct * 16 + ks) * 4 + quad) * 16 + l15;
        *(bf16x8*)(Wf + idx * 8) = cvt8(a, b);
    } else {
        int n = (blk - 1000) * 256 + t; // 16384 chunks
        int r = n >> 6;                 // x row 0..255 (one wave == one row)
        int j = n & 63;
        const float* src = x + r * D_ + j * 8;
        float4 a = *(const float4*)src;
        float4 b = *(const float4*)(src + 4);
        int bt = r >> 4, l15 = r & 15, ks = j >> 2, quad = j & 3;
        int idx = ((bt * 16 + ks) * 4 + quad) * 16 + l15;
        *(bf16x8*)(xf + idx * 8) = cvt8(a, b);
        float sn = a.x*a.x + a.y*a.y + a.z*a.z + a.w*a.w
                 + b.x*b.x + b.y*b.y + b.z*b.z + b.w*b.w;
        #pragma unroll
        for (int o = 32; o; o >>= 1) sn += __shfl_down(sn, o);
        if ((t & 63) == 0) invx[r] = 1.0f / fmaxf(sqrtf(sn), 1e-12f);
    }
}

// Main: logits GEMM + Gram (A·A^T) via MFMA from fragment-linear bf16 panels,
// fused normalize + quadratic-form epilogue.
// D layout of 16x16x32: n=lane&15 -> b, m=quad*4+reg -> (c_local=quad, s=reg).
__global__ __launch_bounds__(256) void k_main(const __bf16* __restrict__ Wf,
                                              const __bf16* __restrict__ xf,
                                              const float* __restrict__ invx,
                                              float* __restrict__ out) {
    int blk = blockIdx.x;
    int ct = blk >> 2;          // 16 W-rows = 4 c's
    int bg = blk & 3;
    int t = threadIdx.x;
    int lane = t & 63, wv = t >> 6;
    int l15 = lane & 15, quad = lane >> 4;
    int bt = bg * 4 + wv;       // b-tile of 16 rows

    const bf16x8* A = (const bf16x8*)Wf + (ct * 64 + quad) * 16 + l15;  // stride 64/ks
    const bf16x8* Bp = (const bf16x8*)xf + (bt * 64 + quad) * 16 + l15;

    f32x4 acc_l = {0.f, 0.f, 0.f, 0.f};
    f32x4 acc_g = {0.f, 0.f, 0.f, 0.f};
    #pragma unroll
    for (int ks = 0; ks < 16; ks++) {
        bf16x8 af = A[ks * 64];
        bf16x8 bf = Bp[ks * 64];
        acc_l = __builtin_amdgcn_mfma_f32_16x16x32_bf16(af, bf, acc_l, 0, 0, 0);
        acc_g = __builtin_amdgcn_mfma_f32_16x16x32_bf16(af, af, acc_g, 0, 0, 0);
    }

    float ivx = invx[bt * 16 + l15];

    // lane's 4x4 Gram block: Gram[4q+s][4q+qq] lives in lane 20*quad+qq, reg s
    float g[4][4];
    #pragma unroll
    for (int s = 0; s < 4; s++) {
        float v = acc_g[s];
        #pragma unroll
        for (int q = 0; q < 4; q++) g[s][q] = __shfl(v, 20 * quad + q);
    }

    float iv[4], l[4];
    #pragma unroll
    for (int s = 0; s < 4; s++) iv[s] = 1.0f / fmaxf(sqrtf(fmaxf(g[s][s], 0.f)), 1e-12f);
    #pragma unroll
    for (int s = 0; s < 4; s++) l[s] = acc_l[s] * ivx * iv[s];

    float num = l[0]*l[0] + l[1]*l[1] + l[2]*l[2] + l[3]*l[3];
    float den2 = 0.f;
    #pragma unroll
    for (int s = 0; s < 4; s++) {
        float r = 0.f;
        #pragma unroll
        for (int q = 0; q < 4; q++) r += g[s][q] * iv[q] * l[q];
        den2 += l[s] * iv[s] * r;
    }
    float den = fmaxf(sqrtf(fmaxf(den2, 0.f)), 1e-12f);
    float val = num / den;

    // pack 4 c's per b into one 16B store (c = ct*4 + quad, contiguous)
    float4 o;
    o.x = __shfl(val, l15);
    o.y = __shfl(val, l15 + 16);
    o.z = __shfl(val, l15 + 32);
    o.w = __shfl(val, l15 + 48);
    if (quad == 0)
        *(float4*)(out + (bt * 16 + l15) * C_ + ct * 4) = o;
}

extern "C" void kernel_launch(void* const* d_in, const int* in_sizes, int n_in,
                              void* d_out, int out_size, void* d_ws, size_t ws_size,
                              hipStream_t stream) {
    const float* x = (const float*)d_in[0];   // [256,512] fp32
    const float* W = (const float*)d_in[1];   // [1000,4,512] fp32
    float* out = (float*)d_out;               // [256,1000] fp32

    char* ws = (char*)d_ws;
    __bf16* Wf  = (__bf16*)ws;                         // 4000*512*2 = 4,096,000 B
    __bf16* xf  = (__bf16*)(ws + 8192000);             // 256*512*2 = 262,144 B... (bytes: 524,288)
    float*  ivx = (float*)(ws + 8192000 + 524288);     // 1024 B

    k_pack<<<1064, 256, 0, stream>>>(x, W, Wf, xf, ivx);
    k_main<<<1000, 256, 0, stream>>>(Wf, xf, ivx, out);
}

// Round 4
// 69.156 us; speedup vs baseline: 1.2850x; 1.0094x over previous
//
#include <hip/hip_runtime.h>

#define B_ 256
#define C_ 1000
#define D_ 512

typedef __bf16 bf16x4 __attribute__((ext_vector_type(4)));
typedef __bf16 bf16x8 __attribute__((ext_vector_type(8)));
typedef float  f32x4  __attribute__((ext_vector_type(4)));

__device__ __forceinline__ bf16x8 cvt8(float4 a, float4 b) {
    bf16x8 r;
    r[0] = (__bf16)a.x; r[1] = (__bf16)a.y; r[2] = (__bf16)a.z; r[3] = (__bf16)a.w;
    r[4] = (__bf16)b.x; r[5] = (__bf16)b.y; r[6] = (__bf16)b.z; r[7] = (__bf16)b.w;
    return r;
}
__device__ __forceinline__ bf16x4 cvt4(float4 a) {
    bf16x4 r;
    r[0] = (__bf16)a.x; r[1] = (__bf16)a.y; r[2] = (__bf16)a.z; r[3] = (__bf16)a.w;
    return r;
}

// Pack x (512 KB) to bf16 MFMA-fragment layout [bt][ks][quad][l15][8] + invx[b].
// 64 blocks; one wave == one x row; coalesced fp32 reads; tiny scattered writes.
__global__ __launch_bounds__(256) void k_packx(const float* __restrict__ x,
                                               __bf16* __restrict__ xf,
                                               float* __restrict__ invx) {
    int n = blockIdx.x * 256 + threadIdx.x;   // 16384 chunks of 8 elems
    int r = n >> 6;                           // x row 0..255 (wave-uniform)
    int j = n & 63;                           // chunk in row
    const float* src = x + r * D_ + j * 8;
    float4 a = *(const float4*)src;
    float4 b = *(const float4*)(src + 4);
    int bt = r >> 4, l15 = r & 15, ks = j >> 2, quad = j & 3;
    int idx = ((bt * 16 + ks) * 4 + quad) * 16 + l15;
    *(bf16x8*)(xf + idx * 8) = cvt8(a, b);
    float sn = a.x*a.x + a.y*a.y + a.z*a.z + a.w*a.w
             + b.x*b.x + b.y*b.y + b.z*b.z + b.w*b.w;
    #pragma unroll
    for (int o = 32; o; o >>= 1) sn += __shfl_down(sn, o);
    if ((threadIdx.x & 63) == 0) invx[r] = 1.0f / fmaxf(sqrtf(sn), 1e-12f);
}

// Main: per block, LDS-transpose one 16-row W tile (fp32 coalesced -> bf16 frags),
// then MFMA logits (2 b-tiles per wave) + Gram (A*A^T) + fused epilogue.
// LDS frag layout: group g = ks*4+quad at byte g*272 (17 frags pad), frag l15 at +l15*16.
__global__ __launch_bounds__(256, 2) void k_main(const float* __restrict__ W,
                                                 const __bf16* __restrict__ xf,
                                                 const float* __restrict__ invx,
                                                 float* __restrict__ out) {
    __shared__ __align__(16) char smem[64 * 272];
    int blk = blockIdx.x;
    int ct = blk >> 1;          // 0..249: c = 4*ct..4*ct+3
    int bh = blk & 1;           // b half
    int t = threadIdx.x;
    int lane = t & 63, wv = t >> 6;
    int l15 = lane & 15, quad = lane >> 4;

    // ---- prologue: W tile (16 rows x 512 fp32) -> LDS bf16 fragments ----
    const float* wbase = W + ct * 16 * D_;
    #pragma unroll
    for (int p = 0; p < 8; p++) {
        int ch = t + 256 * p;            // 2048 float4 chunks
        int row = ch >> 7, pos = ch & 127;
        float4 v = *(const float4*)(wbase + row * D_ + pos * 4);
        int ks = pos >> 3, qd = (pos >> 1) & 3, off = (pos & 1) * 4;
        *(bf16x4*)(smem + (ks * 4 + qd) * 272 + row * 16 + off * 2) = cvt4(v);
    }
    __syncthreads();

    int bt0 = bh * 8 + wv * 2;           // this wave's 2 b-tiles
    int bt1 = bt0 + 1;
    const bf16x8* xp0 = (const bf16x8*)xf + (bt0 * 64 + quad) * 16 + l15;
    const bf16x8* xp1 = (const bf16x8*)xf + (bt1 * 64 + quad) * 16 + l15;
    const char* lp = smem + quad * 272 + l15 * 16;

    f32x4 acc0 = {0.f, 0.f, 0.f, 0.f};
    f32x4 acc1 = {0.f, 0.f, 0.f, 0.f};
    f32x4 accg = {0.f, 0.f, 0.f, 0.f};
    #pragma unroll
    for (int ks = 0; ks < 16; ks++) {
        bf16x8 af = *(const bf16x8*)(lp + ks * 1088);
        bf16x8 b0 = xp0[ks * 64];
        bf16x8 b1 = xp1[ks * 64];
        acc0 = __builtin_amdgcn_mfma_f32_16x16x32_bf16(af, b0, acc0, 0, 0, 0);
        acc1 = __builtin_amdgcn_mfma_f32_16x16x32_bf16(af, b1, acc1, 0, 0, 0);
        accg = __builtin_amdgcn_mfma_f32_16x16x32_bf16(af, af, accg, 0, 0, 0);
    }

    // lane's 4x4 Gram block: Gram[4q+s][4q+qq] is in lane 20*quad+qq, reg s
    float g[4][4];
    #pragma unroll
    for (int s = 0; s < 4; s++) {
        float v = accg[s];
        #pragma unroll
        for (int q = 0; q < 4; q++) g[s][q] = __shfl(v, 20 * quad + q);
    }
    float iv[4];
    #pragma unroll
    for (int s = 0; s < 4; s++) iv[s] = 1.0f / fmaxf(sqrtf(fmaxf(g[s][s], 0.f)), 1e-12f);

    #pragma unroll
    for (int sub = 0; sub < 2; sub++) {
        int bt = sub ? bt1 : bt0;
        f32x4 acc = sub ? acc1 : acc0;
        float ivx = invx[bt * 16 + l15];
        float l[4];
        #pragma unroll
        for (int s = 0; s < 4; s++) l[s] = acc[s] * ivx * iv[s];
        float num = l[0]*l[0] + l[1]*l[1] + l[2]*l[2] + l[3]*l[3];
        float den2 = 0.f;
        #pragma unroll
        for (int s = 0; s < 4; s++) {
            float r = 0.f;
            #pragma unroll
            for (int q = 0; q < 4; q++) r += g[s][q] * iv[q] * l[q];
            den2 += l[s] * iv[s] * r;
        }
        float den = fmaxf(sqrtf(fmaxf(den2, 0.f)), 1e-12f);
        float val = num / den;

        float4 o;   // pack c = ct*4..ct*4+3 for row b into one 16B store
        o.x = __shfl(val, l15);
        o.y = __shfl(val, l15 + 16);
        o.z = __shfl(val, l15 + 32);
        o.w = __shfl(val, l15 + 48);
        if (quad == 0)
            *(float4*)(out + (bt * 16 + l15) * C_ + ct * 4) = o;
    }
}

extern "C" void kernel_launch(void* const* d_in, const int* in_sizes, int n_in,
                              void* d_out, int out_size, void* d_ws, size_t ws_size,
                              hipStream_t stream) {
    const float* x = (const float*)d_in[0];   // [256,512] fp32
    const float* W = (const float*)d_in[1];   // [1000,4,512] fp32
    float* out = (float*)d_out;               // [256,1000] fp32

    char* ws = (char*)d_ws;
    __bf16* xf  = (__bf16*)ws;                // 256*512*2 = 524,288 B
    float*  ivx = (float*)(ws + 524288);      // 1024 B

    k_packx<<<64, 256, 0, stream>>>(x, xf, ivx);
    k_main<<<500, 256, 0, stream>>>(W, xf, ivx, out);
}